// Round 8
// baseline (4358614.453 us; speedup 1.0000x reference)
//
#include <hip/hip_runtime.h>

#define BB 64
#define TT 512
#define HH 1024
#define OUTN 32000
#define NDOM 8              // 8 domains: 8 batch rows each, ideally 1 XCD each
#define NCB 32              // col-blocks per domain (32 cols each)
#define NWG 256
#define NTH 128             // 2 waves; wave wv owns 16 of the WG's 32 cols
#define SLOT (BB * HH * 2)  // 128 KB per ring slot
#define DSL 16384           // bytes per domain slice in a slot (8 rows x 1024 x 2B)
#define FLAGS_OFF 1024      // [dom 8][64] u32 monotonic wave-flags (2 KB)
#define HBUF_OFF 4096       // ring of 3 slots
// slot layout: [dom 0..7][kb 0..31][row 0..7][col 0..31] bf16 (512 B kb-blocks)
// chunk = 16 B = (row, 8 cols), stored by ONE lane's dwordx4 (atomic unit);
// bit14 of chunk's first u16 = step phase (tanh => bit14 is 0 in data).
// Pure XCD-local domains exchange via sc0 (L1-bypass, own-XCD L2);
// impure domains fall back to sc1 (device scope). Phase verify makes any
// staleness a retry, never a wrong answer.

typedef __attribute__((ext_vector_type(8))) short s16x8;
typedef __attribute__((ext_vector_type(4))) float f32x4;
typedef __attribute__((ext_vector_type(4))) int i32x4;

static __device__ __forceinline__ unsigned short f2bf(float f) {
  union { float f; unsigned u; } a; a.f = f;
  unsigned r = a.u + 0x7fffu + ((a.u >> 16) & 1u);   // RNE
  return (unsigned short)(r >> 16);
}

static __device__ __forceinline__ float ftanh(float x) {
  float e = __expf(2.0f * x);
  return 1.0f - 2.0f * __builtin_amdgcn_rcpf(e + 1.0f);
}

#define ALD(idx, off_lit, vov, SCS)                                        \
  asm volatile("global_load_dwordx4 %0, %1, %2 offset:" #off_lit " " SCS   \
               : "=v"(areg[idx]) : "v"(vov), "s"(hprev) : "memory")

#define LDGRP(base, vov, SCS)                                              \
  ALD(base + 0, 0, vov, SCS);    ALD(base + 1, 512, vov, SCS);             \
  ALD(base + 2, 1024, vov, SCS); ALD(base + 3, 1536, vov, SCS);            \
  ALD(base + 4, 2048, vov, SCS); ALD(base + 5, 2560, vov, SCS);            \
  ALD(base + 6, 3072, vov, SCS); ALD(base + 7, 3584, vov, SCS);

#define STEP_LOOP(SC)                                                       \
  for (int s = 0; s < TT; ++s) {                                            \
    const char* hprev = hbuf + (s % 3) * SLOT + dom * DSL;                  \
    char* hcur = hbuf + ((s + 1) % 3) * SLOT + dom * DSL;                   \
    /* embedding gather (tokens prefetched) — hides under the poll */       \
    float ev[4];                                                            \
    _Pragma("unroll") for (int i = 0; i < 4; ++i)                           \
        ev[i] = Wxh[(size_t)xv[i] * HH + mycol];                            \
    /* 1. cheap poll: 64 wave-flags (256 B) of my domain */                 \
    if (s > 0) {                                                            \
      const unsigned* fp = flagsD + l;                                      \
      int guard = 0; unsigned fv;                                           \
      do {                                                                  \
        asm volatile("global_load_dword %0, %1, off " SC "\n\t"             \
                     "s_waitcnt vmcnt(0)"                                   \
                     : "=v"(fv) : "v"(fp) : "memory");                      \
        if (++guard > (1 << 17)) break;  /* safety valve */                 \
      } while (!__all(fv >= (unsigned)s));                                  \
      __builtin_amdgcn_sched_barrier(0);                                    \
    }                                                                       \
    /* 2. one-shot 16 KB A-load + phase verify (retry rare, L2-cheap) */    \
    i32x4 areg[32];                                                         \
    const unsigned want = ((unsigned)(s & 1)) << 14;                        \
    int guard2 = 0;                                                         \
    for (;;) {                                                              \
      LDGRP(0, vo0, SC) LDGRP(8, vo1, SC) LDGRP(16, vo2, SC)                \
      LDGRP(24, vo3, SC)                                                    \
      asm volatile("s_waitcnt vmcnt(0)" ::: "memory");                      \
      __builtin_amdgcn_sched_barrier(0);                                    \
      unsigned bad = 0;                                                     \
      _Pragma("unroll") for (int kb = 0; kb < 32; ++kb)                     \
          bad |= (((unsigned)areg[kb][0]) ^ want) & 0x4000u;                \
      if (__all(bad == 0)) break;                                           \
      if (++guard2 > (1 << 14)) break;  /* safety valve */                  \
    }                                                                       \
    _Pragma("unroll") for (int kb = 0; kb < 32; ++kb)                       \
        areg[kb][0] &= ~0x4000;                                             \
    /* 3. token prefetch for next step (plain cached) */                    \
    if (s + 1 < TT) {                                                       \
      _Pragma("unroll") for (int i = 0; i < 4; ++i)                         \
          xv[i] = x[xrow[i] + s + 1];                                       \
    }                                                                       \
    /* 4. 32 MFMA, fixed order, 4 chains */                                 \
    f32x4 ac[4];                                                            \
    _Pragma("unroll") for (int c = 0; c < 4; ++c)                           \
        ac[c] = (f32x4){0.f, 0.f, 0.f, 0.f};                                \
    _Pragma("unroll") for (int kb = 0; kb < 32; ++kb) {                     \
      union { i32x4 i; s16x8 s; } a_; a_.i = areg[kb];                      \
      s16x8 b_ = *reinterpret_cast<const s16x8*>(                           \
          &wlds[((kb * 2 + wv) * 64 + l) * 8]);                             \
      ac[kb & 3] = __builtin_amdgcn_mfma_f32_16x16x32_bf16(                 \
          a_.s, b_, ac[kb & 3], 0, 0, 0);                                   \
    }                                                                       \
    f32x4 acc = (ac[0] + ac[1]) + (ac[2] + ac[3]);                          \
    /* 5. epilogue, wave-private (C/D: col=lane&15, row=(lane>>4)*4+i);     \
       only rows 0..7 are real for this domain */                           \
    if (lq < 2) {                                                           \
      _Pragma("unroll") for (int i = 0; i < 4; ++i) {                       \
        float v = ftanh(acc[i] + ev[i] + bias);                             \
        epi[wv * 128 + (lq * 4 + i) * 16 + lr] = f2bf(v);                   \
      }                                                                     \
    }                                                                       \
    asm volatile("s_waitcnt lgkmcnt(0)" ::: "memory");                      \
    __builtin_amdgcn_sched_barrier(0);                                      \
    /* 6. wave stores its 16 chunks (8 rows x its 16 cols), phase-tagged */ \
    if (l < 16) {                                                           \
      int r = l >> 1, hf = l & 1;                                           \
      i32x4 v = *reinterpret_cast<const i32x4*>(                            \
          &epi[wv * 128 + r * 16 + hf * 8]);                                \
      v[0] |= (int)(((unsigned)((s + 1) & 1)) << 14);                       \
      char* dst = hcur + cb * 512 + r * 64 + wv * 32 + hf * 16;             \
      asm volatile("global_store_dwordx4 %0, %1, off " SC                   \
                   :: "v"(dst), "v"(v) : "memory");                         \
    }                                                                       \
    if (l == 0) {                                                           \
      unsigned sv = (unsigned)(s + 1);                                      \
      asm volatile("global_store_dword %0, %1, off " SC                     \
                   :: "v"(flagsD + cb * 2 + wv), "v"(sv) : "memory");       \
    }                                                                       \
  }

__global__ __launch_bounds__(NTH, 1) void rnn_persist(
    const int* __restrict__ x, const float* __restrict__ Wxh,
    const float* __restrict__ Whh_w, const float* __restrict__ Whh_b,
    unsigned* __restrict__ ctl, char* __restrict__ ws) {
  const int tid = threadIdx.x;
  const int wv = tid >> 6;
  const int l = tid & 63;
  const int lr = l & 15;
  const int lq = l >> 4;
  const int lrc = lr < 7 ? lr : 7;   // A rows 8..15 duplicate row 7 (garbage M)

  __shared__ __align__(16) unsigned short wlds[32 * 2 * 64 * 8];  // 64 KB
  __shared__ __align__(16) unsigned short epi[2 * 128];           // per-wave 256B
  __shared__ unsigned sh_role;

  // ---- one-time role assignment: claim a slot on MY XCD ----
  // ctl[0]=done, ctl[1]=ticket, ctl[16..23]=per-XCD claim counters
  if (tid == 0) {
    unsigned xcc = (unsigned)__builtin_amdgcn_s_getreg(63508) & 7u; // XCC_ID
    unsigned slot = __hip_atomic_fetch_add(&ctl[16 + xcc], 1u,
                        __ATOMIC_RELAXED, __HIP_MEMORY_SCOPE_AGENT);
    __hip_atomic_fetch_add(&ctl[0], 1u, __ATOMIC_RELEASE,
                           __HIP_MEMORY_SCOPE_AGENT);
    int guard = 0;
    while (__hip_atomic_load(&ctl[0], __ATOMIC_ACQUIRE,
                             __HIP_MEMORY_SCOPE_AGENT) < (unsigned)NWG) {
      __builtin_amdgcn_s_sleep(8);
      if (++guard > (1 << 20)) break;   // safety valve
    }
    unsigned cnt[8];
    for (int d = 0; d < 8; ++d)
      cnt[d] = __hip_atomic_load(&ctl[16 + d], __ATOMIC_ACQUIRE,
                                 __HIP_MEMORY_SCOPE_AGENT);
    unsigned dm, cbv;
    if (slot < NCB) { dm = xcc; cbv = slot; }
    else {  // overflow: deterministically fill deficit domains
      unsigned t = __hip_atomic_fetch_add(&ctl[1], 1u, __ATOMIC_RELAXED,
                                          __HIP_MEMORY_SCOPE_AGENT);
      unsigned acc2 = 0; dm = 0; cbv = 0;
      for (int d = 0; d < 8; ++d) {
        unsigned def = cnt[d] < NCB ? NCB - cnt[d] : 0;
        if (t < acc2 + def) { dm = d; cbv = cnt[d] + (t - acc2); break; }
        acc2 += def;
      }
    }
    unsigned pure = (cnt[dm] >= NCB) ? 1u : 0u;  // all 32 members XCD-local?
    sh_role = (pure << 16) | (dm << 8) | cbv;
  }
  __syncthreads();
  const unsigned role = sh_role;
  const int dom = (role >> 8) & 0xff;
  const int cb = role & 0xff;
  const bool pure = (role >> 16) != 0;

  char* hbuf = ws + HBUF_OFF;
  unsigned* flagsD = (unsigned*)(ws + FLAGS_OFF) + dom * 64;
  const int mycol = cb * 32 + wv * 16 + lr;
  const unsigned vo0 = (unsigned)(lrc * 64 + lq * 16);
  const unsigned vo1 = vo0 + 4096, vo2 = vo0 + 8192, vo3 = vo0 + 12288;

  // ---- one-time B pack: Whh^T slice -> LDS, MFMA B-fragment order ----
  for (int e = tid; e < 32 * 2 * 64; e += NTH) {
    int kb = e >> 7;
    int nt = (e >> 6) & 1;
    int ln = e & 63;
    int col = cb * 32 + nt * 16 + (ln & 15);
    int k0 = kb * 32 + (ln >> 4) * 8;
    const float* src = Whh_w + (size_t)col * HH + k0;
    union { unsigned short u[8]; i32x4 v; } pk;
    #pragma unroll
    for (int j = 0; j < 8; ++j) pk.u[j] = f2bf(src[j]);
    *reinterpret_cast<i32x4*>(&wlds[(size_t)e * 8]) = pk.v;
  }
  const float bias = Whh_b[mycol];
  __syncthreads();

  // token row bases (rows clamped inside the domain's 8)
  int xrow[4], xv[4];
  #pragma unroll
  for (int i = 0; i < 4; ++i) {
    int rr = lq * 4 + i; if (rr > 7) rr = 7;
    xrow[i] = (dom * 8 + rr) * TT;
    xv[i] = x[xrow[i]];
  }

  if (pure) {
    STEP_LOOP("sc0")          // XCD-local: L1-bypass, served by own L2
  } else {
    STEP_LOOP("sc1")          // cross-XCD fallback: device scope (MALL)
  }
}

// out[64][32000] = h_final @ Why^T + Why_b; h_512 = ring slot 2 (512%3==2),
// phase bit (512&1)==0 -> clean. End-of-kernel release flushes XCD L2s.
__global__ __launch_bounds__(256) void rnn_proj(
    const char* __restrict__ hfin, const float* __restrict__ Why_w,
    const float* __restrict__ Why_b, float* __restrict__ out) {
  const int tid = threadIdx.x;
  const int w = tid >> 6;
  const int l = tid & 63;
  const int lr = l & 15;
  const int lq = l >> 4;
  const int nbase = blockIdx.x * 128;
  const int row = w * 16 + lr;

  f32x4 acc[8];
  #pragma unroll
  for (int nt = 0; nt < 8; ++nt) acc[nt] = (f32x4){0.f, 0.f, 0.f, 0.f};

  const char* abase = hfin + (size_t)(row >> 3) * DSL + (row & 7) * 64 + lq * 16;
  for (int kb = 0; kb < 32; ++kb) {
    s16x8 a = *reinterpret_cast<const s16x8*>(abase + kb * 512);
    #pragma unroll
    for (int nt = 0; nt < 8; ++nt) {
      int n = nbase + nt * 16 + lr;
      const float* wp = Why_w + (size_t)n * HH + kb * 32 + lq * 8;
      union { unsigned short u[8]; s16x8 v; } bb;
      #pragma unroll
      for (int j = 0; j < 8; ++j) bb.u[j] = f2bf(wp[j]);
      acc[nt] = __builtin_amdgcn_mfma_f32_16x16x32_bf16(a, bb.v, acc[nt], 0, 0, 0);
    }
  }
  #pragma unroll
  for (int nt = 0; nt < 8; ++nt) {
    int n = nbase + nt * 16 + lr;
    float bv = Why_b[n];
    #pragma unroll
    for (int i = 0; i < 4; ++i) {
      int b = w * 16 + lq * 4 + i;
      out[(size_t)b * OUTN + n] = acc[nt][i] + bv;
    }
  }
}

extern "C" void kernel_launch(void* const* d_in, const int* in_sizes, int n_in,
                              void* d_out, int out_size, void* d_ws, size_t ws_size,
                              hipStream_t stream) {
  const int* x = (const int*)d_in[0];
  const float* Wxh = (const float*)d_in[1];
  const float* Whh_w = (const float*)d_in[2];
  const float* Whh_b = (const float*)d_in[3];
  const float* Why_w = (const float*)d_in[4];
  const float* Why_b = (const float*)d_in[5];
  float* out = (float*)d_out;

  unsigned* ctl = (unsigned*)d_ws;
  char* ws = (char*)d_ws;
  char* hbuf = ws + HBUF_OFF;

  // ctl+flags=0; slot0 = h_0 = zeros (phase0 valid); slot1 = 0x00 (!=phase1);
  // slot2 = 0x40 (bit14=1 != phase0). Re-done every call — deterministic.
  hipMemsetAsync(ws, 0x00, HBUF_OFF + 2 * SLOT, stream);
  hipMemsetAsync(hbuf + 2 * SLOT, 0x40, SLOT, stream);
  rnn_persist<<<NWG, NTH, 0, stream>>>(x, Wxh, Whh_w, Whh_b, ctl, ws);
  rnn_proj<<<OUTN / 128, 256, 0, stream>>>(hbuf + 2 * SLOT, Why_w, Why_b, out);
}

// Round 9
// 2109.248 us; speedup vs baseline: 2066.4309x; 2066.4309x over previous
//
#include <hip/hip_runtime.h>

#define BB 64
#define TT 512
#define HH 1024
#define OUTN 32000
#define NDOM 4              // 4 independent domains: 16 batch rows each
#define NCB 32              // col-blocks per domain (32 cols each)
#define NWG (NDOM * NCB)    // 128 workgroups
#define NTH 128             // 2 waves; wave wv owns 16 of the WG's 32 cols
#define SLOT (BB * HH * 2)  // 128 KB per ring slot
#define FLAGS_BYTES 4096
// ws: [flags 4KB][ring of 3 slots x 128 KB]
// slot layout: [dom 0..3][kb 0..31][row 0..15][col 0..31] bf16
// chunk = 16 B, one lane's dwordx4 (atomic unit); bit14 of chunk's first u16
// = step phase (tanh => bit14 is 0 in data).
// flags[dom*32+cb]: monotonic counter bumped by global_atomic_add (no-return)
// AFTER the producer's data stores are acked -> flag>=s PROVES data visible.

typedef __attribute__((ext_vector_type(8))) short s16x8;
typedef __attribute__((ext_vector_type(4))) float f32x4;
typedef __attribute__((ext_vector_type(4))) int i32x4;

static __device__ __forceinline__ unsigned short f2bf(float f) {
  union { float f; unsigned u; } a; a.f = f;
  unsigned r = a.u + 0x7fffu + ((a.u >> 16) & 1u);   // RNE
  return (unsigned short)(r >> 16);
}

static __device__ __forceinline__ float ftanh(float x) {
  float e = __expf(2.0f * x);
  return 1.0f - 2.0f * __builtin_amdgcn_rcpf(e + 1.0f);
}

#define ALD(idx, off_lit, vov)                                            \
  asm volatile("global_load_dwordx4 %0, %1, %2 offset:" #off_lit " sc1"   \
               : "=v"(areg[idx]) : "v"(vov), "s"(hprev) : "memory")

// issue all 32 A-chunk loads in areg order (exact vmcnt accounting)
#define ISSUEA                                                             \
  ALD(0,0,vo0);  ALD(1,1024,vo0);  ALD(2,2048,vo0);  ALD(3,3072,vo0);      \
  ALD(4,0,vo1);  ALD(5,1024,vo1);  ALD(6,2048,vo1);  ALD(7,3072,vo1);      \
  ALD(8,0,vo2);  ALD(9,1024,vo2);  ALD(10,2048,vo2); ALD(11,3072,vo2);     \
  ALD(12,0,vo3); ALD(13,1024,vo3); ALD(14,2048,vo3); ALD(15,3072,vo3);     \
  ALD(16,0,vo4); ALD(17,1024,vo4); ALD(18,2048,vo4); ALD(19,3072,vo4);     \
  ALD(20,0,vo5); ALD(21,1024,vo5); ALD(22,2048,vo5); ALD(23,3072,vo5);     \
  ALD(24,0,vo6); ALD(25,1024,vo6); ALD(26,2048,vo6); ALD(27,3072,vo6);     \
  ALD(28,0,vo7); ALD(29,1024,vo7); ALD(30,2048,vo7); ALD(31,3072,vo7);

#define WAITV(n)                                                           \
  do { asm volatile("s_waitcnt vmcnt(" #n ")" ::: "memory");               \
       __builtin_amdgcn_sched_barrier(0); } while (0)

// record phase-bit mismatches and clear the bit (group of 8 kb-blocks)
#define CLRG(g)                                                            \
  { _Pragma("unroll") for (int j = 0; j < 8; ++j) {                        \
      unsigned u0 = (unsigned)areg[(g) * 8 + j][0];                        \
      bad |= (u0 ^ want) & 0x4000u;                                        \
      areg[(g) * 8 + j][0] = (int)(u0 & ~0x4000u); } }

// MFMA one group of 8 kb-blocks, fixed order, 4 independent chains
#define MFG(g)                                                             \
  { _Pragma("unroll") for (int j = 0; j < 8; ++j) {                        \
      union { i32x4 i; s16x8 s; } a_; a_.i = areg[(g) * 8 + j];            \
      s16x8 b_ = *reinterpret_cast<const s16x8*>(                          \
          &wlds[((((g) * 8 + j) * 2 + wv) * 64 + l) * 8]);                 \
      ac[j & 3] = __builtin_amdgcn_mfma_f32_16x16x32_bf16(                 \
          a_.s, b_, ac[j & 3], 0, 0, 0); } }

__global__ __launch_bounds__(NTH, 1) void rnn_persist(
    const int* __restrict__ x, const float* __restrict__ Wxh,
    const float* __restrict__ Whh_w, const float* __restrict__ Whh_b,
    unsigned* __restrict__ flags, char* __restrict__ hbuf) {
  const int g = blockIdx.x;
  const int dom = g >> 5;          // batch rows [16*dom, +16)
  const int cb = g & 31;           // cols [32*cb, +32)
  const int tid = threadIdx.x;
  const int wv = tid >> 6;
  const int l = tid & 63;
  const int lr = l & 15;
  const int lq = l >> 4;

  __shared__ __align__(16) unsigned short wlds[32 * 2 * 64 * 8];  // 64 KB B-frags
  __shared__ __align__(16) unsigned short epi[16 * 32];           // 1 KB repack

  // One-time B pack (MFMA B-fragment order)
  for (int e = tid; e < 32 * 2 * 64; e += NTH) {
    int kb = e >> 7;
    int nt = (e >> 6) & 1;
    int ln = e & 63;
    int col = cb * 32 + nt * 16 + (ln & 15);
    int k0 = kb * 32 + (ln >> 4) * 8;
    const float* src = Whh_w + (size_t)col * HH + k0;
    union { unsigned short u[8]; i32x4 v; } pk;
    #pragma unroll
    for (int j = 0; j < 8; ++j) pk.u[j] = f2bf(src[j]);
    *reinterpret_cast<i32x4*>(&wlds[(size_t)e * 8]) = pk.v;
  }
  const int mycol = cb * 32 + wv * 16 + lr;
  const float bias = Whh_b[mycol];
  __syncthreads();

  int xrow[4], xv[4];
  #pragma unroll
  for (int i = 0; i < 4; ++i) {
    xrow[i] = (dom * 16 + lq * 4 + i) * TT;
    xv[i] = x[xrow[i]];
  }

  unsigned* flagsD = flags + dom * 32;
  const unsigned vo0 = (unsigned)(lr * 64 + lq * 16);
  const unsigned vo1 = vo0 + 4096, vo2 = vo0 + 8192, vo3 = vo0 + 12288;
  const unsigned vo4 = vo0 + 16384, vo5 = vo0 + 20480, vo6 = vo0 + 24576,
                 vo7 = vo0 + 28672;

  for (int s = 0; s < TT; ++s) {
    const char* hprev = hbuf + (s % 3) * SLOT + dom * 32768;
    char* hcur = hbuf + ((s + 1) % 3) * SLOT + dom * 32768;

    // 1. poll FIRST (nothing else in the vmem queue but last step's acks):
    //    flag >= s proves step s-1 data is at the coherent point.
    if (s > 0) {
      const unsigned* fp = flagsD + (l & 31);
      int guard = 0;
      unsigned fv;
      do {
        asm volatile("global_load_dword %0, %1, off sc1\n\t"
                     "s_waitcnt vmcnt(0)"
                     : "=v"(fv) : "v"(fp) : "memory");
        if (++guard > (1 << 17)) break;   // safety valve
      } while (!__all(fv >= (unsigned)s));
      __builtin_amdgcn_sched_barrier(0);
    }

    // 2. issue A-loads (32), then ev gather (4), then next-step x (4) —
    //    all inline asm so vmcnt counts are exact (queue = 40).
    i32x4 areg[32];
    ISSUEA;
    unsigned evu[4];
    #pragma unroll
    for (int i = 0; i < 4; ++i) {
      const float* ep = Wxh + (size_t)xv[i] * HH + mycol;
      asm volatile("global_load_dword %0, %1, off"
                   : "=v"(evu[i]) : "v"(ep) : "memory");
    }
    {
      int snext = (s + 1 < TT) ? (s + 1) : s;   // always 4 loads (count!)
      #pragma unroll
      for (int i = 0; i < 4; ++i) {
        const int* xp = x + xrow[i] + snext;
        asm volatile("global_load_dword %0, %1, off"
                     : "=v"(xv[i]) : "v"(xp) : "memory");
      }
    }

    // 3. pipelined gates: verify+clear+MFMA per 8-block group
    const unsigned want = ((unsigned)(s & 1)) << 14;
    unsigned bad = 0;
    f32x4 ac[4];
    #pragma unroll
    for (int c = 0; c < 4; ++c) ac[c] = (f32x4){0.f, 0.f, 0.f, 0.f};
    WAITV(32); CLRG(0); MFG(0);
    WAITV(24); CLRG(1); MFG(1);
    WAITV(16); CLRG(2); MFG(2);
    WAITV(8);  CLRG(3); MFG(3);
    WAITV(0);                      // ev + x landed
    if (!__all(bad == 0)) {
      // safety net (flag ordering makes this near-impossible): full redo
      int guard2 = 0;
      for (;;) {
        ISSUEA;
        asm volatile("s_waitcnt vmcnt(0)" ::: "memory");
        __builtin_amdgcn_sched_barrier(0);
        bad = 0;
        CLRG(0); CLRG(1); CLRG(2); CLRG(3);
        if (__all(bad == 0)) break;
        if (++guard2 > (1 << 15)) break;   // never hard-wedge
      }
      #pragma unroll
      for (int c = 0; c < 4; ++c) ac[c] = (f32x4){0.f, 0.f, 0.f, 0.f};
      MFG(0); MFG(1); MFG(2); MFG(3);
    }
    f32x4 acc = (ac[0] + ac[1]) + (ac[2] + ac[3]);

    // 4. epilogue: C/D col=lane&15, row=(lane>>4)*4+i -> LDS repack [row][col]
    #pragma unroll
    for (int i = 0; i < 4; ++i) {
      union { unsigned u; float f; } cv; cv.u = evu[i];
      float v = ftanh(acc[i] + cv.f + bias);
      epi[(lq * 4 + i) * 32 + wv * 16 + lr] = f2bf(v);
    }
    __syncthreads();

    // 5. wave0: one wave-wide 1KB block store (phase-tagged), ACK, then the
    //    monotonic flag bump via no-return atomic (MALL-resident line).
    if (tid < 64) {
      i32x4 v = *reinterpret_cast<const i32x4*>(&epi[tid * 8]);
      v[0] |= (int)(((unsigned)((s + 1) & 1)) << 14);
      char* dst = hcur + cb * 1024 + tid * 16;
      asm volatile("global_store_dwordx4 %0, %1, off sc1"
                   :: "v"(dst), "v"(v) : "memory");
      asm volatile("s_waitcnt vmcnt(0)" ::: "memory");   // data acked
      if (tid == 0) {
        unsigned* fp = flagsD + cb;
        unsigned one = 1u;
        asm volatile("global_atomic_add %0, %1, off"
                     :: "v"(fp), "v"(one) : "memory");
      }
    }
  }
}

// out[64][32000] = h_final @ Why^T + Why_b; h_512 = ring slot 2 (512%3==2),
// phase bit (512&1)==0 -> data is clean, no fixup.
__global__ __launch_bounds__(256) void rnn_proj(
    const char* __restrict__ hfin, const float* __restrict__ Why_w,
    const float* __restrict__ Why_b, float* __restrict__ out) {
  const int tid = threadIdx.x;
  const int w = tid >> 6;
  const int l = tid & 63;
  const int lr = l & 15;
  const int lq = l >> 4;
  const int nbase = blockIdx.x * 128;
  const int row = w * 16 + lr;

  f32x4 acc[8];
  #pragma unroll
  for (int nt = 0; nt < 8; ++nt) acc[nt] = (f32x4){0.f, 0.f, 0.f, 0.f};

  const char* abase = hfin + (size_t)(row >> 4) * 32768 + (row & 15) * 64 + lq * 16;
  for (int kb = 0; kb < 32; ++kb) {
    s16x8 a = *reinterpret_cast<const s16x8*>(abase + kb * 1024);
    #pragma unroll
    for (int nt = 0; nt < 8; ++nt) {
      int n = nbase + nt * 16 + lr;
      const float* wp = Why_w + (size_t)n * HH + kb * 32 + lq * 8;
      union { unsigned short u[8]; s16x8 v; } bb;
      #pragma unroll
      for (int j = 0; j < 8; ++j) bb.u[j] = f2bf(wp[j]);
      acc[nt] = __builtin_amdgcn_mfma_f32_16x16x32_bf16(a, bb.v, acc[nt], 0, 0, 0);
    }
  }
  #pragma unroll
  for (int nt = 0; nt < 8; ++nt) {
    int n = nbase + nt * 16 + lr;
    float bv = Why_b[n];
    #pragma unroll
    for (int i = 0; i < 4; ++i) {
      int b = w * 16 + lq * 4 + i;
      out[(size_t)b * OUTN + n] = acc[nt][i] + bv;
    }
  }
}

extern "C" void kernel_launch(void* const* d_in, const int* in_sizes, int n_in,
                              void* d_out, int out_size, void* d_ws, size_t ws_size,
                              hipStream_t stream) {
  const int* x = (const int*)d_in[0];
  const float* Wxh = (const float*)d_in[1];
  const float* Whh_w = (const float*)d_in[2];
  const float* Whh_b = (const float*)d_in[3];
  const float* Why_w = (const float*)d_in[4];
  const float* Why_b = (const float*)d_in[5];
  float* out = (float*)d_out;

  unsigned* flags = (unsigned*)d_ws;
  char* hbuf = (char*)d_ws + FLAGS_BYTES;

  // flags=0; slot0 = h_0 = zeros (phase0 valid); slot1 = 0x00 (bit14=0 !=
  // phase1); slot2 = 0x40 (bit14=1 != phase0). Re-done every call.
  hipMemsetAsync(d_ws, 0x00, FLAGS_BYTES + 2 * SLOT, stream);
  hipMemsetAsync(hbuf + 2 * SLOT, 0x40, SLOT, stream);
  rnn_persist<<<NWG, NTH, 0, stream>>>(x, Wxh, Whh_w, Whh_b, flags, hbuf);
  rnn_proj<<<OUTN / 128, 256, 0, stream>>>(hbuf + 2 * SLOT, Why_w, Why_b, out);
}